// Round 8
// baseline (233.707 us; speedup 1.0000x reference)
//
#include <hip/hip_runtime.h>
#include <hip/hip_bf16.h>

// CHNN=1024, K=L=2048. Inputs fp32, output fp32. bf16 MFMA (16x16x32), fp32
// acc, TN layout. Round 20 = r19 + PAIR-TILES: each single wave computes a
// 64x128 tile (two 64x64 outputs) sharing its staged A-tile. Per K-step:
// 12 global_load_lds (4 A + 8 B) + 32 MFMA vs 2x(8+16) -> staged bytes/FLOP
// -25%, MFMA density x2, still barrier-free (no cross-wave coupling).
// Same XOR slot-swizzle + depth-3 prefetch, waits vmcnt(24)/12/0.
// LDS 36KB -> 4 blocks/CU; __launch_bounds__(64,1) (acc=128 VGPR).
// L5 keeps r19's symmetric triangular 64x64 path. 7 launches unchanged.

typedef __bf16 bf16x4 __attribute__((ext_vector_type(4)));
typedef __bf16 bf16x8 __attribute__((ext_vector_type(8)));
typedef float  f32x4  __attribute__((ext_vector_type(4)));

typedef const void __attribute__((address_space(1)))* gptr_t;
typedef void       __attribute__((address_space(3)))* lptr_t;

__device__ __forceinline__ void load16_lds(const __bf16* g, __bf16* l)
{
    __builtin_amdgcn_global_load_lds((gptr_t)g, (lptr_t)l, 16, 0, 0);
}

// s_waitcnt imm (gfx9): vmcnt[3:0]@0 + vmcnt[5:4]@14, expcnt[6:4], lgkmcnt[11:8]
#define WAITCNT_VM24 0x4F78  // vmcnt(24)
#define WAITCNT_VM16 0x4F70  // vmcnt(16)
#define WAITCNT_VM12 0x0F7C  // vmcnt(12)
#define WAITCNT_VM8  0x0F78  // vmcnt(8)
#define WAITCNT_VM0  0x0F70  // vmcnt(0)

template<typename OT, int BIAS_, bool RELU_, int STORE_>
struct GC {
    using OUT_T = OT;
    static constexpr int BIAS = BIAS_, STORE = STORE_;
    static constexpr bool RELU = RELU_;
};

// ---------- 64x64 single-tile body (used only by symmetric L5) ----------
template<class CF>
__device__ __forceinline__ void gemm_body(
    int bid, __bf16* sA, __bf16* sB,
    const __bf16* __restrict__ A, const __bf16* __restrict__ B,
    const float* __restrict__ bias,
    typename CF::OUT_T* __restrict__ C, typename CF::OUT_T* __restrict__ CT,
    int M, int N, int K, int ntx, bool mirror = false)
{
    const int lane = threadIdx.x & 63;
    const int m0 = (bid / ntx) * 64, n0 = (bid % ntx) * 64;
    const __bf16* gA = A + (size_t)m0 * K;
    const __bf16* gB = B + (size_t)n0 * K;

    f32x4 acc[4][4];
    #pragma unroll
    for (int i = 0; i < 4; ++i)
        #pragma unroll
        for (int j = 0; j < 4; ++j)
            acc[i][j] = (f32x4){0.f, 0.f, 0.f, 0.f};

    auto stage = [&](int k0, int buf) {
        #pragma unroll
        for (int i = 0; i < 4; ++i) {
            const int c = i * 64 + lane;
            const int s = (c ^ (c >> 2) ^ (c >> 4)) & 3;
            load16_lds(gA + (size_t)(c >> 2) * K + k0 + s * 8,
                       &sA[buf * 2048 + i * 512]);
        }
        #pragma unroll
        for (int i = 0; i < 4; ++i) {
            const int c = i * 64 + lane;
            const int s = (c ^ (c >> 2) ^ (c >> 4)) & 3;
            load16_lds(gB + (size_t)(c >> 2) * K + k0 + s * 8,
                       &sB[buf * 2048 + i * 512]);
        }
    };

    const int fsw = ((lane >> 4) ^ lane ^ (lane >> 2)) & 3;

    auto compute = [&](int buf) {
        bf16x8 af[4], bfr[4];
        #pragma unroll
        for (int i = 0; i < 4; ++i) {
            const int off = buf * 2048 + (i * 16 + (lane & 15)) * 32 + fsw * 8;
            af[i]  = *(const bf16x8*)&sA[off];
            bfr[i] = *(const bf16x8*)&sB[off];
        }
        #pragma unroll
        for (int i = 0; i < 4; ++i)
            #pragma unroll
            for (int j = 0; j < 4; ++j)
                acc[i][j] = __builtin_amdgcn_mfma_f32_16x16x32_bf16(af[i], bfr[j], acc[i][j], 0, 0, 0);
    };

    stage(0, 0);
    stage(32, 1);
    stage(64, 2);
    int cur = 0;
    for (int k0 = 0; k0 < K - 96; k0 += 32) {
        __builtin_amdgcn_s_waitcnt(WAITCNT_VM16);
        compute(cur);
        stage(k0 + 96, cur);
        cur = (cur == 2) ? 0 : cur + 1;
    }
    __builtin_amdgcn_s_waitcnt(WAITCNT_VM16);
    compute(cur); cur = (cur == 2) ? 0 : cur + 1;
    __builtin_amdgcn_s_waitcnt(WAITCNT_VM8);
    compute(cur); cur = (cur == 2) ? 0 : cur + 1;
    __builtin_amdgcn_s_waitcnt(WAITCNT_VM0);
    compute(cur);

    // Epilogue. C/D layout: col=lane&15, row=(lane>>4)*4+reg.
    #pragma unroll
    for (int i = 0; i < 4; ++i) {
        const int rowb = m0 + i * 16 + (lane >> 4) * 4;
        #pragma unroll
        for (int j = 0; j < 4; ++j) {
            const int col = n0 + j * 16 + (lane & 15);
            f32x4 v = acc[i][j];
            #pragma unroll
            for (int r = 0; r < 4; ++r) {
                float f = v[r];
                if constexpr (CF::BIAS == 1) f += bias[rowb + r];
                if constexpr (CF::BIAS == 2) f += bias[col];
                if constexpr (CF::RELU) f = fmaxf(f, 0.f);
                v[r] = f;
            }
            if constexpr (CF::STORE == 0) {
                #pragma unroll
                for (int r = 0; r < 4; ++r)
                    C[(size_t)(rowb + r) * N + col] = (typename CF::OUT_T)v[r];
                if constexpr (sizeof(typename CF::OUT_T) == 2) {
                    if (mirror) {
                        bf16x4 w = { (__bf16)v[0], (__bf16)v[1],
                                     (__bf16)v[2], (__bf16)v[3] };
                        *(bf16x4*)&C[(size_t)col * N + rowb] = w;
                    }
                }
            } else {
                if constexpr (sizeof(typename CF::OUT_T) == 4) {
                    *(f32x4*)&CT[(size_t)col * M + rowb] = v;
                } else {
                    bf16x4 w = { (__bf16)v[0], (__bf16)v[1], (__bf16)v[2], (__bf16)v[3] };
                    *(bf16x4*)&CT[(size_t)col * M + rowb] = w;
                }
            }
        }
    }
}

// ---------- 64x128 pair-tile body (all other GEMM layers) ----------
// C(M,N) = A(M,K)*B(N,K)^T, one wave: rows [m0,m0+64) x cols [n0,n0+128).
// sA: 3 x 4KB (64x32), sB: 3 x 8KB (128x32). ntx = N/128.
template<class CF>
__device__ __forceinline__ void gemm_body2(
    int bid, __bf16* sA, __bf16* sB,
    const __bf16* __restrict__ A, const __bf16* __restrict__ B,
    const float* __restrict__ bias,
    typename CF::OUT_T* __restrict__ C, typename CF::OUT_T* __restrict__ CT,
    int M, int N, int K, int ntx)
{
    const int lane = threadIdx.x & 63;
    const int m0 = (bid / ntx) * 64, n0 = (bid % ntx) * 128;
    const __bf16* gA = A + (size_t)m0 * K;
    const __bf16* gB = B + (size_t)n0 * K;

    f32x4 acc[2][4][4];
    #pragma unroll
    for (int h = 0; h < 2; ++h)
        #pragma unroll
        for (int i = 0; i < 4; ++i)
            #pragma unroll
            for (int j = 0; j < 4; ++j)
                acc[h][i][j] = (f32x4){0.f, 0.f, 0.f, 0.f};

    // stage 64x32 A (4 instr) + 128x32 B (8 instr), XOR slot-swizzle applied
    // on the global source; LDS dest linear (base + lane*16).
    auto stage = [&](int k0, int buf) {
        #pragma unroll
        for (int i = 0; i < 4; ++i) {
            const int c = i * 64 + lane;
            const int s = (c ^ (c >> 2) ^ (c >> 4)) & 3;
            load16_lds(gA + (size_t)(c >> 2) * K + k0 + s * 8,
                       &sA[buf * 2048 + i * 512]);
        }
        #pragma unroll
        for (int i = 0; i < 8; ++i) {
            const int c = i * 64 + lane;
            const int s = (c ^ (c >> 2) ^ (c >> 4)) & 3;
            load16_lds(gB + (size_t)(c >> 2) * K + k0 + s * 8,
                       &sB[buf * 4096 + i * 512]);
        }
    };

    auto compute = [&](int buf) {
        bf16x8 af[4];
        #pragma unroll
        for (int i = 0; i < 4; ++i) {
            const int ra = i * 16 + (lane & 15);
            const int sa = ((lane >> 4) ^ ra ^ (ra >> 2)) & 3;
            af[i] = *(const bf16x8*)&sA[buf * 2048 + ra * 32 + sa * 8];
        }
        #pragma unroll
        for (int h = 0; h < 2; ++h) {
            bf16x8 bfr[4];
            #pragma unroll
            for (int j = 0; j < 4; ++j) {
                const int rb = h * 64 + j * 16 + (lane & 15);
                const int sb = ((lane >> 4) ^ rb ^ (rb >> 2)) & 3;
                bfr[j] = *(const bf16x8*)&sB[buf * 4096 + rb * 32 + sb * 8];
            }
            #pragma unroll
            for (int i = 0; i < 4; ++i)
                #pragma unroll
                for (int j = 0; j < 4; ++j)
                    acc[h][i][j] = __builtin_amdgcn_mfma_f32_16x16x32_bf16(
                        af[i], bfr[j], acc[h][i][j], 0, 0, 0);
        }
    };

    stage(0, 0);
    stage(32, 1);
    stage(64, 2);
    int cur = 0;
    for (int k0 = 0; k0 < K - 96; k0 += 32) {
        __builtin_amdgcn_s_waitcnt(WAITCNT_VM24);   // cur's 12 loads retired
        compute(cur);
        stage(k0 + 96, cur);
        cur = (cur == 2) ? 0 : cur + 1;
    }
    __builtin_amdgcn_s_waitcnt(WAITCNT_VM24);
    compute(cur); cur = (cur == 2) ? 0 : cur + 1;
    __builtin_amdgcn_s_waitcnt(WAITCNT_VM12);
    compute(cur); cur = (cur == 2) ? 0 : cur + 1;
    __builtin_amdgcn_s_waitcnt(WAITCNT_VM0);
    compute(cur);

    // Epilogue for both halves.
    #pragma unroll
    for (int h = 0; h < 2; ++h) {
        #pragma unroll
        for (int i = 0; i < 4; ++i) {
            const int rowb = m0 + i * 16 + (lane >> 4) * 4;
            #pragma unroll
            for (int j = 0; j < 4; ++j) {
                const int col = n0 + h * 64 + j * 16 + (lane & 15);
                f32x4 v = acc[h][i][j];
                #pragma unroll
                for (int r = 0; r < 4; ++r) {
                    float f = v[r];
                    if constexpr (CF::BIAS == 1) f += bias[rowb + r];
                    if constexpr (CF::BIAS == 2) f += bias[col];
                    if constexpr (CF::RELU) f = fmaxf(f, 0.f);
                    v[r] = f;
                }
                if constexpr (CF::STORE == 0) {
                    #pragma unroll
                    for (int r = 0; r < 4; ++r)
                        C[(size_t)(rowb + r) * N + col] = (typename CF::OUT_T)v[r];
                } else {
                    if constexpr (sizeof(typename CF::OUT_T) == 4) {
                        *(f32x4*)&CT[(size_t)col * M + rowb] = v;
                    } else {
                        bf16x4 w = { (__bf16)v[0], (__bf16)v[1], (__bf16)v[2], (__bf16)v[3] };
                        *(bf16x4*)&CT[(size_t)col * M + rowb] = w;
                    }
                }
            }
        }
    }
}

// Single-wave row softmax over 2048 bf16 (32 elems/lane, shuffle reduce).
__device__ __forceinline__ void softmax_row_w(__bf16* __restrict__ p)
{
    const int lane = threadIdx.x & 63;
    bf16x8 v[4];
    float f[32];
    #pragma unroll
    for (int r = 0; r < 4; ++r)
        v[r] = *(const bf16x8*)&p[(r * 64 + lane) * 8];
    float m = -1e30f;
    #pragma unroll
    for (int r = 0; r < 4; ++r)
        #pragma unroll
        for (int j = 0; j < 8; ++j) {
            f[r * 8 + j] = (float)v[r][j];
            m = fmaxf(m, f[r * 8 + j]);
        }
    #pragma unroll
    for (int s = 1; s < 64; s <<= 1) m = fmaxf(m, __shfl_xor(m, s, 64));
    float sum = 0.f;
    #pragma unroll
    for (int i = 0; i < 32; ++i) { f[i] = expf(f[i] - m); sum += f[i]; }
    #pragma unroll
    for (int s = 1; s < 64; s <<= 1) sum += __shfl_xor(sum, s, 64);
    const float inv = 1.f / sum;
    #pragma unroll
    for (int r = 0; r < 4; ++r) {
        bf16x8 w;
        #pragma unroll
        for (int j = 0; j < 8; ++j) w[j] = (__bf16)(f[r * 8 + j] * inv);
        *(bf16x8*)&p[(r * 64 + lane) * 8] = w;
    }
}

template<class CF>
__global__ __launch_bounds__(64, 1)
void gemm1w(const __bf16* __restrict__ A, const __bf16* __restrict__ B,
            const float* __restrict__ bias,
            typename CF::OUT_T* __restrict__ C, typename CF::OUT_T* __restrict__ CT,
            int M, int N, int K, int ntx)
{
    __shared__ __bf16 sAB[18432];   // sA 3x2048 + sB 3x4096 = 36 KB
    gemm_body2<CF>(blockIdx.x, sAB, sAB + 6144, A, B, bias, C, CT, M, N, K, ntx);
}

// Triangular symmetric GEMM (64x64 body): C = A*A^T, upper tiles + mirror.
template<class CF>
__global__ __launch_bounds__(64, 2)
void gemm1wsym(const __bf16* __restrict__ A,
               typename CF::OUT_T* __restrict__ C,
               int M, int K, int ntx)
{
    __shared__ __bf16 sAB[12288];
    int rem = blockIdx.x, ti = 0, rowlen = ntx;
    while (rem >= rowlen) { rem -= rowlen; ++ti; --rowlen; }
    const int tj = ti + rem;
    gemm_body<CF>(ti * ntx + tj, sAB, sAB + 6144, A, A, nullptr, C,
                  (typename CF::OUT_T*)nullptr, M, M, K, ntx, ti != tj);
}

// Two GEMMs fused (pair-tile body).
template<class C1, class C2>
__global__ __launch_bounds__(64, 1)
void gemm2w(int nblk1,
            const __bf16* __restrict__ A1, const __bf16* __restrict__ B1,
            const float* __restrict__ b1,
            typename C1::OUT_T* __restrict__ C1p, typename C1::OUT_T* __restrict__ CT1,
            int M1, int N1, int K1, int ntx1,
            const __bf16* __restrict__ A2, const __bf16* __restrict__ B2,
            const float* __restrict__ b2,
            typename C2::OUT_T* __restrict__ C2p, typename C2::OUT_T* __restrict__ CT2,
            int M2, int N2, int K2, int ntx2)
{
    __shared__ __bf16 sAB[18432];
    const int b = blockIdx.x;
    if (b < nblk1)
        gemm_body2<C1>(b, sAB, sAB + 6144, A1, B1, b1, C1p, CT1, M1, N1, K1, ntx1);
    else
        gemm_body2<C2>(b - nblk1, sAB, sAB + 6144, A2, B2, b2, C2p, CT2, M2, N2, K2, ntx2);
}

// Two GEMMs + row-softmax batch fused (pair-tile body).
template<class C1, class C2>
__global__ __launch_bounds__(64, 1)
void gemm2smw(int nblk1, int nblk2,
              const __bf16* __restrict__ A1, const __bf16* __restrict__ B1,
              const float* __restrict__ b1, typename C1::OUT_T* __restrict__ C1p,
              int M1, int N1, int K1, int ntx1,
              const __bf16* __restrict__ A2, const __bf16* __restrict__ B2,
              const float* __restrict__ b2, typename C2::OUT_T* __restrict__ C2p,
              int M2, int N2, int K2, int ntx2,
              __bf16* __restrict__ SM)
{
    __shared__ __bf16 sAB[18432];
    const int b = blockIdx.x;
    if (b < nblk1)
        gemm_body2<C1>(b, sAB, sAB + 6144, A1, B1, b1, C1p,
                       (typename C1::OUT_T*)nullptr, M1, N1, K1, ntx1);
    else if (b < nblk1 + nblk2)
        gemm_body2<C2>(b - nblk1, sAB, sAB + 6144, A2, B2, b2, C2p,
                       (typename C2::OUT_T*)nullptr, M2, N2, K2, ntx2);
    else
        softmax_row_w(SM + (size_t)(b - nblk1 - nblk2) * 2048);
}

__global__ __launch_bounds__(64)
void row_softmax_w(__bf16* __restrict__ A)
{
    softmax_row_w(A + (size_t)blockIdx.x * 2048);
}

// ---------------- prep (unchanged, 256-thread) ----------------
__device__ __forceinline__ void tp_tile(const float* __restrict__ in,
                                        __bf16* __restrict__ outp,
                                        int R, int C, int bx, int by)
{
    __shared__ float t[32][33];
    const int tx = threadIdx.x & 31, ty = threadIdx.x >> 5;
    #pragma unroll
    for (int i = ty; i < 32; i += 8)
        t[i][tx] = in[(size_t)(by + i) * C + (bx + tx)];
    __syncthreads();
    #pragma unroll
    for (int i = ty; i < 32; i += 8)
        outp[(size_t)(bx + i) * R + (by + tx)] = (__bf16)t[tx][i];
}

__device__ __forceinline__ void cast_blk(const float* __restrict__ s,
                                         __bf16* __restrict__ d, int blk)
{
    const int i = blk * 1024 + threadIdx.x * 4;
    float4 v = *(const float4*)&s[i];
    bf16x4 w = { (__bf16)v.x, (__bf16)v.y, (__bf16)v.z, (__bf16)v.w };
    *(bf16x4*)&d[i] = w;
}

__global__ __launch_bounds__(256)
void prep(const float* __restrict__ vc, __bf16* __restrict__ vcT,
          const float* __restrict__ vm, __bf16* __restrict__ vmT,
          const float* __restrict__ W_ak, __bf16* __restrict__ W_akb,
          const float* __restrict__ W_c, __bf16* __restrict__ W_cb,
          const float* __restrict__ W_mad, __bf16* __restrict__ W_madb,
          const float* __restrict__ W_gcn, __bf16* __restrict__ W_gcnT)
{
    const int x = blockIdx.x;
    if (blockIdx.z == 0) {
        const float* in = (x < 2048) ? vc : vm;
        __bf16* o       = (x < 2048) ? vcT : vmT;
        const int e = x & 2047;
        tp_tile(in, o, 1024, 2048, (e & 63) * 32, (e >> 6) * 32);
    } else if (blockIdx.z == 1) {
        if (x < 2048)      cast_blk(W_ak, W_akb, x);
        else if (x < 3072) cast_blk(W_c, W_cb, x - 2048);
        else               cast_blk(W_mad, W_madb, x - 3072);
    } else {
        if (x >= 1024) return;
        tp_tile(W_gcn, W_gcnT, 1024, 1024, (x & 31) * 32, (x >> 5) * 32);
    }
}

extern "C" void kernel_launch(void* const* d_in, const int* in_sizes, int n_in,
                              void* d_out, int out_size, void* d_ws, size_t ws_size,
                              hipStream_t stream)
{
    const float* vc    = (const float*)d_in[0];
    const float* vm    = (const float*)d_in[1];
    const float* W_ak  = (const float*)d_in[2];
    const float* b_ak  = (const float*)d_in[3];
    const float* W_c   = (const float*)d_in[4];
    const float* b_c   = (const float*)d_in[5];
    const float* W_mad = (const float*)d_in[6];
    const float* b_mad = (const float*)d_in[7];
    const float* W_gcn = (const float*)d_in[8];
    const float* b_gcn = (const float*)d_in[9];
    float* out = (float*)d_out;

    // Arena, 32 MB (r13 layout):
    //  [0,8):   ST (wL2, smL3, rL4)  -> P (wL5, smL6, rL7)
    //  [8,12):  vcT (wL1, rL2)       -> vmaT (wL4, rL5)
    //  [12,16): W_akb (wL1, rL2)     -> vmm (wL3, rL4)
    //  [16,20): vmT (wL1, rL2)       -> xT (wL3, rL7)
    //  [20,22): W_cb (wL1, rL2)
    //  [22,24): W_madb (wL1, rL3)
    //  [24,28): vmrT (wL2, rL3)
    //  [28,30): W_gcnT (wL1, rL3)
    char* ws = (char*)d_ws;
    const size_t MB = 1u << 20;
    __bf16* ST     = (__bf16*)(ws);
    __bf16* P      = (__bf16*)(ws);
    __bf16* vcT    = (__bf16*)(ws + 8 * MB);
    __bf16* vmaT   = (__bf16*)(ws + 8 * MB);
    __bf16* W_akb  = (__bf16*)(ws + 12 * MB);
    __bf16* vmm    = (__bf16*)(ws + 12 * MB);
    __bf16* vmT    = (__bf16*)(ws + 16 * MB);
    __bf16* xT     = (__bf16*)(ws + 16 * MB);
    __bf16* W_cb   = (__bf16*)(ws + 20 * MB);
    __bf16* W_madb = (__bf16*)(ws + 22 * MB);
    __bf16* vmrT   = (__bf16*)(ws + 24 * MB);
    __bf16* W_gcnT = (__bf16*)(ws + 28 * MB);

    using G3  = GC<__bf16, 2, false, 0>;   // ST = vcT*W_akb + b_ak[col]
    using G5  = GC<__bf16, 1, true,  1>;   // vmrT = relu(W_cb*vmT + b_c[row])^T
    using G6  = GC<__bf16, 0, false, 0>;   // vmm = W_madb*vmrT
    using G11 = GC<__bf16, 1, false, 0>;   // xT = W_gcnT*vmrT + b_gcn[row]
    using G7  = GC<__bf16, 2, false, 0>;   // vmaT = ST_sm*vmm + b_mad[col]
    using G9  = GC<__bf16, 0, false, 0>;   // P = vmaT*vmaT^T (symmetric)
    using G12 = GC<float,  0, false, 1>;   // out = (P_sm*xT)^T fp32

    // L1. input casts/transposes
    prep<<<dim3(4096, 1, 3), 256, 0, stream>>>(vc, vcT, vm, vmT, W_ak, W_akb,
                                               W_c, W_cb, W_mad, W_madb,
                                               W_gcn, W_gcnT);
    // L2. [G3 512 | G5 256] = 768 pair-tile blocks (ntx = N/128)
    gemm2w<G3, G5><<<768, 64, 0, stream>>>(512,
        vcT, W_akb, b_ak, ST, (__bf16*)nullptr, 2048, 2048, 1024, 16,
        W_cb, vmT, b_c, (__bf16*)nullptr, vmrT, 1024, 2048, 1024, 16);
    // L3. [G6 256 | G11 256 | smST 2048] = 2560 blocks
    gemm2smw<G6, G11><<<2560, 64, 0, stream>>>(256, 256,
        W_madb, vmrT, nullptr, vmm, 1024, 2048, 1024, 16,
        W_gcnT, vmrT, b_gcn, xT, 1024, 2048, 1024, 16,
        ST);
    // L4. G7: vmaT = ST_sm*vmm + b_mad (2048x1024 K2048), 256 pair blocks
    gemm1w<G7><<<256, 64, 0, stream>>>(ST, vmm, b_mad, vmaT, (__bf16*)nullptr,
                                       2048, 1024, 2048, 8);
    // L5. G9: P = vmaT*vmaT^T symmetric (2048x2048 K1024), 528 tri blocks
    gemm1wsym<G9><<<528, 64, 0, stream>>>(vmaT, P, 2048, 1024, 32);
    // L6. softmax rows of P
    row_softmax_w<<<2048, 64, 0, stream>>>(P);
    // L7. G12: out = (P_sm*xT)^T direct fp32 (2048x1024 K2048), 256 pair blocks
    gemm1w<G12><<<256, 64, 0, stream>>>(P, xT, nullptr, (float*)nullptr, out,
                                        2048, 1024, 2048, 8);
}

// Round 9
// 197.372 us; speedup vs baseline: 1.1841x; 1.1841x over previous
//
#include <hip/hip_runtime.h>
#include <hip/hip_bf16.h>

// CHNN=1024, K=L=2048. Inputs fp32, output fp32. bf16 MFMA (16x16x32), fp32
// acc, TN layout. Round 21 = r19 + pair-tiles ONLY where occupancy allows:
// L2/L3 use 64x128 pair-tile waves (768 / 2560 blocks = 3+/CU, bytes -23%);
// L4/L5/L6/L7 are byte-identical to r19 (64x64 bodies, 512/528/512 blocks =
// 2/CU — r20 showed 1 blk/CU starves the BW-bound big-K layers).
// All GEMM waves barrier-free, XOR slot-swizzle, depth-3 global_load_lds
// prefetch. L5 symmetric triangular. 7 launches.

typedef __bf16 bf16x4 __attribute__((ext_vector_type(4)));
typedef __bf16 bf16x8 __attribute__((ext_vector_type(8)));
typedef float  f32x4  __attribute__((ext_vector_type(4)));

typedef const void __attribute__((address_space(1)))* gptr_t;
typedef void       __attribute__((address_space(3)))* lptr_t;

__device__ __forceinline__ void load16_lds(const __bf16* g, __bf16* l)
{
    __builtin_amdgcn_global_load_lds((gptr_t)g, (lptr_t)l, 16, 0, 0);
}

// s_waitcnt imm (gfx9): vmcnt[3:0]@0 + vmcnt[5:4]@14, expcnt[6:4], lgkmcnt[11:8]
#define WAITCNT_VM24 0x4F78  // vmcnt(24)
#define WAITCNT_VM16 0x4F70  // vmcnt(16)
#define WAITCNT_VM12 0x0F7C  // vmcnt(12)
#define WAITCNT_VM8  0x0F78  // vmcnt(8)
#define WAITCNT_VM0  0x0F70  // vmcnt(0)

template<typename OT, int BIAS_, bool RELU_, int STORE_>
struct GC {
    using OUT_T = OT;
    static constexpr int BIAS = BIAS_, STORE = STORE_;
    static constexpr bool RELU = RELU_;
};

// ---------- 64x64 single-tile body (L4, L5-symmetric, L7) ----------
template<class CF>
__device__ __forceinline__ void gemm_body(
    int bid, __bf16* sA, __bf16* sB,
    const __bf16* __restrict__ A, const __bf16* __restrict__ B,
    const float* __restrict__ bias,
    typename CF::OUT_T* __restrict__ C, typename CF::OUT_T* __restrict__ CT,
    int M, int N, int K, int ntx, bool mirror = false)
{
    const int lane = threadIdx.x & 63;
    const int m0 = (bid / ntx) * 64, n0 = (bid % ntx) * 64;
    const __bf16* gA = A + (size_t)m0 * K;
    const __bf16* gB = B + (size_t)n0 * K;

    f32x4 acc[4][4];
    #pragma unroll
    for (int i = 0; i < 4; ++i)
        #pragma unroll
        for (int j = 0; j < 4; ++j)
            acc[i][j] = (f32x4){0.f, 0.f, 0.f, 0.f};

    auto stage = [&](int k0, int buf) {
        #pragma unroll
        for (int i = 0; i < 4; ++i) {
            const int c = i * 64 + lane;
            const int s = (c ^ (c >> 2) ^ (c >> 4)) & 3;
            load16_lds(gA + (size_t)(c >> 2) * K + k0 + s * 8,
                       &sA[buf * 2048 + i * 512]);
        }
        #pragma unroll
        for (int i = 0; i < 4; ++i) {
            const int c = i * 64 + lane;
            const int s = (c ^ (c >> 2) ^ (c >> 4)) & 3;
            load16_lds(gB + (size_t)(c >> 2) * K + k0 + s * 8,
                       &sB[buf * 2048 + i * 512]);
        }
    };

    const int fsw = ((lane >> 4) ^ lane ^ (lane >> 2)) & 3;

    auto compute = [&](int buf) {
        bf16x8 af[4], bfr[4];
        #pragma unroll
        for (int i = 0; i < 4; ++i) {
            const int off = buf * 2048 + (i * 16 + (lane & 15)) * 32 + fsw * 8;
            af[i]  = *(const bf16x8*)&sA[off];
            bfr[i] = *(const bf16x8*)&sB[off];
        }
        #pragma unroll
        for (int i = 0; i < 4; ++i)
            #pragma unroll
            for (int j = 0; j < 4; ++j)
                acc[i][j] = __builtin_amdgcn_mfma_f32_16x16x32_bf16(af[i], bfr[j], acc[i][j], 0, 0, 0);
    };

    stage(0, 0);
    stage(32, 1);
    stage(64, 2);
    int cur = 0;
    for (int k0 = 0; k0 < K - 96; k0 += 32) {
        __builtin_amdgcn_s_waitcnt(WAITCNT_VM16);
        compute(cur);
        stage(k0 + 96, cur);
        cur = (cur == 2) ? 0 : cur + 1;
    }
    __builtin_amdgcn_s_waitcnt(WAITCNT_VM16);
    compute(cur); cur = (cur == 2) ? 0 : cur + 1;
    __builtin_amdgcn_s_waitcnt(WAITCNT_VM8);
    compute(cur); cur = (cur == 2) ? 0 : cur + 1;
    __builtin_amdgcn_s_waitcnt(WAITCNT_VM0);
    compute(cur);

    // Epilogue. C/D layout: col=lane&15, row=(lane>>4)*4+reg (verified r6-r11).
    #pragma unroll
    for (int i = 0; i < 4; ++i) {
        const int rowb = m0 + i * 16 + (lane >> 4) * 4;
        #pragma unroll
        for (int j = 0; j < 4; ++j) {
            const int col = n0 + j * 16 + (lane & 15);
            f32x4 v = acc[i][j];
            #pragma unroll
            for (int r = 0; r < 4; ++r) {
                float f = v[r];
                if constexpr (CF::BIAS == 1) f += bias[rowb + r];
                if constexpr (CF::BIAS == 2) f += bias[col];
                if constexpr (CF::RELU) f = fmaxf(f, 0.f);
                v[r] = f;
            }
            if constexpr (CF::STORE == 0) {
                #pragma unroll
                for (int r = 0; r < 4; ++r)
                    C[(size_t)(rowb + r) * N + col] = (typename CF::OUT_T)v[r];
                if constexpr (sizeof(typename CF::OUT_T) == 2) {
                    if (mirror) {
                        bf16x4 w = { (__bf16)v[0], (__bf16)v[1],
                                     (__bf16)v[2], (__bf16)v[3] };
                        *(bf16x4*)&C[(size_t)col * N + rowb] = w;
                    }
                }
            } else {
                if constexpr (sizeof(typename CF::OUT_T) == 4) {
                    *(f32x4*)&CT[(size_t)col * M + rowb] = v;
                } else {
                    bf16x4 w = { (__bf16)v[0], (__bf16)v[1], (__bf16)v[2], (__bf16)v[3] };
                    *(bf16x4*)&CT[(size_t)col * M + rowb] = w;
                }
            }
        }
    }
}

// ---------- 64x128 pair-tile body (L2/L3 only: grids >= 3 blocks/CU) ----------
// One wave: rows [m0,m0+64) x cols [n0,n0+128), shared staged A-tile.
// sA: 3 x 4KB (64x32), sB: 3 x 8KB (128x32). ntx = N/128.
template<class CF>
__device__ __forceinline__ void gemm_body2(
    int bid, __bf16* sA, __bf16* sB,
    const __bf16* __restrict__ A, const __bf16* __restrict__ B,
    const float* __restrict__ bias,
    typename CF::OUT_T* __restrict__ C, typename CF::OUT_T* __restrict__ CT,
    int M, int N, int K, int ntx)
{
    const int lane = threadIdx.x & 63;
    const int m0 = (bid / ntx) * 64, n0 = (bid % ntx) * 128;
    const __bf16* gA = A + (size_t)m0 * K;
    const __bf16* gB = B + (size_t)n0 * K;

    f32x4 acc[2][4][4];
    #pragma unroll
    for (int h = 0; h < 2; ++h)
        #pragma unroll
        for (int i = 0; i < 4; ++i)
            #pragma unroll
            for (int j = 0; j < 4; ++j)
                acc[h][i][j] = (f32x4){0.f, 0.f, 0.f, 0.f};

    auto stage = [&](int k0, int buf) {
        #pragma unroll
        for (int i = 0; i < 4; ++i) {
            const int c = i * 64 + lane;
            const int s = (c ^ (c >> 2) ^ (c >> 4)) & 3;
            load16_lds(gA + (size_t)(c >> 2) * K + k0 + s * 8,
                       &sA[buf * 2048 + i * 512]);
        }
        #pragma unroll
        for (int i = 0; i < 8; ++i) {
            const int c = i * 64 + lane;
            const int s = (c ^ (c >> 2) ^ (c >> 4)) & 3;
            load16_lds(gB + (size_t)(c >> 2) * K + k0 + s * 8,
                       &sB[buf * 4096 + i * 512]);
        }
    };

    auto compute = [&](int buf) {
        bf16x8 af[4];
        #pragma unroll
        for (int i = 0; i < 4; ++i) {
            const int ra = i * 16 + (lane & 15);
            const int sa = ((lane >> 4) ^ ra ^ (ra >> 2)) & 3;
            af[i] = *(const bf16x8*)&sA[buf * 2048 + ra * 32 + sa * 8];
        }
        #pragma unroll
        for (int h = 0; h < 2; ++h) {
            bf16x8 bfr[4];
            #pragma unroll
            for (int j = 0; j < 4; ++j) {
                const int rb = h * 64 + j * 16 + (lane & 15);
                const int sb = ((lane >> 4) ^ rb ^ (rb >> 2)) & 3;
                bfr[j] = *(const bf16x8*)&sB[buf * 4096 + rb * 32 + sb * 8];
            }
            #pragma unroll
            for (int i = 0; i < 4; ++i)
                #pragma unroll
                for (int j = 0; j < 4; ++j)
                    acc[h][i][j] = __builtin_amdgcn_mfma_f32_16x16x32_bf16(
                        af[i], bfr[j], acc[h][i][j], 0, 0, 0);
        }
    };

    stage(0, 0);
    stage(32, 1);
    stage(64, 2);
    int cur = 0;
    for (int k0 = 0; k0 < K - 96; k0 += 32) {
        __builtin_amdgcn_s_waitcnt(WAITCNT_VM24);   // cur's 12 loads retired
        compute(cur);
        stage(k0 + 96, cur);
        cur = (cur == 2) ? 0 : cur + 1;
    }
    __builtin_amdgcn_s_waitcnt(WAITCNT_VM24);
    compute(cur); cur = (cur == 2) ? 0 : cur + 1;
    __builtin_amdgcn_s_waitcnt(WAITCNT_VM12);
    compute(cur); cur = (cur == 2) ? 0 : cur + 1;
    __builtin_amdgcn_s_waitcnt(WAITCNT_VM0);
    compute(cur);

    #pragma unroll
    for (int h = 0; h < 2; ++h) {
        #pragma unroll
        for (int i = 0; i < 4; ++i) {
            const int rowb = m0 + i * 16 + (lane >> 4) * 4;
            #pragma unroll
            for (int j = 0; j < 4; ++j) {
                const int col = n0 + h * 64 + j * 16 + (lane & 15);
                f32x4 v = acc[h][i][j];
                #pragma unroll
                for (int r = 0; r < 4; ++r) {
                    float f = v[r];
                    if constexpr (CF::BIAS == 1) f += bias[rowb + r];
                    if constexpr (CF::BIAS == 2) f += bias[col];
                    if constexpr (CF::RELU) f = fmaxf(f, 0.f);
                    v[r] = f;
                }
                if constexpr (CF::STORE == 0) {
                    #pragma unroll
                    for (int r = 0; r < 4; ++r)
                        C[(size_t)(rowb + r) * N + col] = (typename CF::OUT_T)v[r];
                } else {
                    if constexpr (sizeof(typename CF::OUT_T) == 4) {
                        *(f32x4*)&CT[(size_t)col * M + rowb] = v;
                    } else {
                        bf16x4 w = { (__bf16)v[0], (__bf16)v[1], (__bf16)v[2], (__bf16)v[3] };
                        *(bf16x4*)&CT[(size_t)col * M + rowb] = w;
                    }
                }
            }
        }
    }
}

// Single-wave row softmax over 2048 bf16 (32 elems/lane, shuffle reduce).
__device__ __forceinline__ void softmax_row_w(__bf16* __restrict__ p)
{
    const int lane = threadIdx.x & 63;
    bf16x8 v[4];
    float f[32];
    #pragma unroll
    for (int r = 0; r < 4; ++r)
        v[r] = *(const bf16x8*)&p[(r * 64 + lane) * 8];
    float m = -1e30f;
    #pragma unroll
    for (int r = 0; r < 4; ++r)
        #pragma unroll
        for (int j = 0; j < 8; ++j) {
            f[r * 8 + j] = (float)v[r][j];
            m = fmaxf(m, f[r * 8 + j]);
        }
    #pragma unroll
    for (int s = 1; s < 64; s <<= 1) m = fmaxf(m, __shfl_xor(m, s, 64));
    float sum = 0.f;
    #pragma unroll
    for (int i = 0; i < 32; ++i) { f[i] = expf(f[i] - m); sum += f[i]; }
    #pragma unroll
    for (int s = 1; s < 64; s <<= 1) sum += __shfl_xor(sum, s, 64);
    const float inv = 1.f / sum;
    #pragma unroll
    for (int r = 0; r < 4; ++r) {
        bf16x8 w;
        #pragma unroll
        for (int j = 0; j < 8; ++j) w[j] = (__bf16)(f[r * 8 + j] * inv);
        *(bf16x8*)&p[(r * 64 + lane) * 8] = w;
    }
}

// 64x64 single-tile kernel (L4, L7): 24KB LDS, 2+ blocks/CU.
template<class CF>
__global__ __launch_bounds__(64, 2)
void gemm1w(const __bf16* __restrict__ A, const __bf16* __restrict__ B,
            const float* __restrict__ bias,
            typename CF::OUT_T* __restrict__ C, typename CF::OUT_T* __restrict__ CT,
            int M, int N, int K, int ntx)
{
    __shared__ __bf16 sAB[12288];   // sA 3x2048 + sB 3x2048 = 24 KB
    gemm_body<CF>(blockIdx.x, sAB, sAB + 6144, A, B, bias, C, CT, M, N, K, ntx);
}

// Triangular symmetric GEMM (64x64 body): C = A*A^T, upper tiles + mirror.
template<class CF>
__global__ __launch_bounds__(64, 2)
void gemm1wsym(const __bf16* __restrict__ A,
               typename CF::OUT_T* __restrict__ C,
               int M, int K, int ntx)
{
    __shared__ __bf16 sAB[12288];
    int rem = blockIdx.x, ti = 0, rowlen = ntx;
    while (rem >= rowlen) { rem -= rowlen; ++ti; --rowlen; }
    const int tj = ti + rem;
    gemm_body<CF>(ti * ntx + tj, sAB, sAB + 6144, A, A, nullptr, C,
                  (typename CF::OUT_T*)nullptr, M, M, K, ntx, ti != tj);
}

// Two GEMMs fused, pair-tile body (L2). 36KB LDS.
template<class C1, class C2>
__global__ __launch_bounds__(64, 1)
void gemm2w(int nblk1,
            const __bf16* __restrict__ A1, const __bf16* __restrict__ B1,
            const float* __restrict__ b1,
            typename C1::OUT_T* __restrict__ C1p, typename C1::OUT_T* __restrict__ CT1,
            int M1, int N1, int K1, int ntx1,
            const __bf16* __restrict__ A2, const __bf16* __restrict__ B2,
            const float* __restrict__ b2,
            typename C2::OUT_T* __restrict__ C2p, typename C2::OUT_T* __restrict__ CT2,
            int M2, int N2, int K2, int ntx2)
{
    __shared__ __bf16 sAB[18432];
    const int b = blockIdx.x;
    if (b < nblk1)
        gemm_body2<C1>(b, sAB, sAB + 6144, A1, B1, b1, C1p, CT1, M1, N1, K1, ntx1);
    else
        gemm_body2<C2>(b - nblk1, sAB, sAB + 6144, A2, B2, b2, C2p, CT2, M2, N2, K2, ntx2);
}

// Two GEMMs + row-softmax batch fused, pair-tile body (L3). 36KB LDS.
template<class C1, class C2>
__global__ __launch_bounds__(64, 1)
void gemm2smw(int nblk1, int nblk2,
              const __bf16* __restrict__ A1, const __bf16* __restrict__ B1,
              const float* __restrict__ b1, typename C1::OUT_T* __restrict__ C1p,
              int M1, int N1, int K1, int ntx1,
              const __bf16* __restrict__ A2, const __bf16* __restrict__ B2,
              const float* __restrict__ b2, typename C2::OUT_T* __restrict__ C2p,
              int M2, int N2, int K2, int ntx2,
              __bf16* __restrict__ SM)
{
    __shared__ __bf16 sAB[18432];
    const int b = blockIdx.x;
    if (b < nblk1)
        gemm_body2<C1>(b, sAB, sAB + 6144, A1, B1, b1, C1p,
                       (typename C1::OUT_T*)nullptr, M1, N1, K1, ntx1);
    else if (b < nblk1 + nblk2)
        gemm_body2<C2>(b - nblk1, sAB, sAB + 6144, A2, B2, b2, C2p,
                       (typename C2::OUT_T*)nullptr, M2, N2, K2, ntx2);
    else
        softmax_row_w(SM + (size_t)(b - nblk1 - nblk2) * 2048);
}

__global__ __launch_bounds__(64)
void row_softmax_w(__bf16* __restrict__ A)
{
    softmax_row_w(A + (size_t)blockIdx.x * 2048);
}

// ---------------- prep (unchanged, 256-thread) ----------------
__device__ __forceinline__ void tp_tile(const float* __restrict__ in,
                                        __bf16* __restrict__ outp,
                                        int R, int C, int bx, int by)
{
    __shared__ float t[32][33];
    const int tx = threadIdx.x & 31, ty = threadIdx.x >> 5;
    #pragma unroll
    for (int i = ty; i < 32; i += 8)
        t[i][tx] = in[(size_t)(by + i) * C + (bx + tx)];
    __syncthreads();
    #pragma unroll
    for (int i = ty; i < 32; i += 8)
        outp[(size_t)(bx + i) * R + (by + tx)] = (__bf16)t[tx][i];
}

__device__ __forceinline__ void cast_blk(const float* __restrict__ s,
                                         __bf16* __restrict__ d, int blk)
{
    const int i = blk * 1024 + threadIdx.x * 4;
    float4 v = *(const float4*)&s[i];
    bf16x4 w = { (__bf16)v.x, (__bf16)v.y, (__bf16)v.z, (__bf16)v.w };
    *(bf16x4*)&d[i] = w;
}

__global__ __launch_bounds__(256)
void prep(const float* __restrict__ vc, __bf16* __restrict__ vcT,
          const float* __restrict__ vm, __bf16* __restrict__ vmT,
          const float* __restrict__ W_ak, __bf16* __restrict__ W_akb,
          const float* __restrict__ W_c, __bf16* __restrict__ W_cb,
          const float* __restrict__ W_mad, __bf16* __restrict__ W_madb,
          const float* __restrict__ W_gcn, __bf16* __restrict__ W_gcnT)
{
    const int x = blockIdx.x;
    if (blockIdx.z == 0) {
        const float* in = (x < 2048) ? vc : vm;
        __bf16* o       = (x < 2048) ? vcT : vmT;
        const int e = x & 2047;
        tp_tile(in, o, 1024, 2048, (e & 63) * 32, (e >> 6) * 32);
    } else if (blockIdx.z == 1) {
        if (x < 2048)      cast_blk(W_ak, W_akb, x);
        else if (x < 3072) cast_blk(W_c, W_cb, x - 2048);
        else               cast_blk(W_mad, W_madb, x - 3072);
    } else {
        if (x >= 1024) return;
        tp_tile(W_gcn, W_gcnT, 1024, 1024, (x & 31) * 32, (x >> 5) * 32);
    }
}

extern "C" void kernel_launch(void* const* d_in, const int* in_sizes, int n_in,
                              void* d_out, int out_size, void* d_ws, size_t ws_size,
                              hipStream_t stream)
{
    const float* vc    = (const float*)d_in[0];
    const float* vm    = (const float*)d_in[1];
    const float* W_ak  = (const float*)d_in[2];
    const float* b_ak  = (const float*)d_in[3];
    const float* W_c   = (const float*)d_in[4];
    const float* b_c   = (const float*)d_in[5];
    const float* W_mad = (const float*)d_in[6];
    const float* b_mad = (const float*)d_in[7];
    const float* W_gcn = (const float*)d_in[8];
    const float* b_gcn = (const float*)d_in[9];
    float* out = (float*)d_out;

    // Arena, 32 MB (r13 layout):
    //  [0,8):   ST (wL2, smL3, rL4)  -> P (wL5, smL6, rL7)
    //  [8,12):  vcT (wL1, rL2)       -> vmaT (wL4, rL5)
    //  [12,16): W_akb (wL1, rL2)     -> vmm (wL3, rL4)
    //  [16,20): vmT (wL1, rL2)       -> xT (wL3, rL7)
    //  [20,22): W_cb (wL1, rL2)
    //  [22,24): W_madb (wL1, rL3)
    //  [24,28): vmrT (wL2, rL3)
    //  [28,30): W_gcnT (wL1, rL3)
    char* ws = (char*)d_ws;
    const size_t MB = 1u << 20;
    __bf16* ST     = (__bf16*)(ws);
    __bf16* P      = (__bf16*)(ws);
    __bf16* vcT    = (__bf16*)(ws + 8 * MB);
    __bf16* vmaT   = (__bf16*)(ws + 8 * MB);
    __bf16* W_akb  = (__bf16*)(ws + 12 * MB);
    __bf16* vmm    = (__bf16*)(ws + 12 * MB);
    __bf16* vmT    = (__bf16*)(ws + 16 * MB);
    __bf16* xT     = (__bf16*)(ws + 16 * MB);
    __bf16* W_cb   = (__bf16*)(ws + 20 * MB);
    __bf16* W_madb = (__bf16*)(ws + 22 * MB);
    __bf16* vmrT   = (__bf16*)(ws + 24 * MB);
    __bf16* W_gcnT = (__bf16*)(ws + 28 * MB);

    using G3  = GC<__bf16, 2, false, 0>;   // ST = vcT*W_akb + b_ak[col]
    using G5  = GC<__bf16, 1, true,  1>;   // vmrT = relu(W_cb*vmT + b_c[row])^T
    using G6  = GC<__bf16, 0, false, 0>;   // vmm = W_madb*vmrT
    using G11 = GC<__bf16, 1, false, 0>;   // xT = W_gcnT*vmrT + b_gcn[row]
    using G7  = GC<__bf16, 2, false, 0>;   // vmaT = ST_sm*vmm + b_mad[col]
    using G9  = GC<__bf16, 0, false, 0>;   // P = vmaT*vmaT^T (symmetric)
    using G12 = GC<float,  0, false, 1>;   // out = (P_sm*xT)^T fp32

    // L1. input casts/transposes
    prep<<<dim3(4096, 1, 3), 256, 0, stream>>>(vc, vcT, vm, vmT, W_ak, W_akb,
                                               W_c, W_cb, W_mad, W_madb,
                                               W_gcn, W_gcnT);
    // L2. [G3 512 | G5 256] = 768 pair-tile blocks (ntx = N/128), 3/CU
    gemm2w<G3, G5><<<768, 64, 0, stream>>>(512,
        vcT, W_akb, b_ak, ST, (__bf16*)nullptr, 2048, 2048, 1024, 16,
        W_cb, vmT, b_c, (__bf16*)nullptr, vmrT, 1024, 2048, 1024, 16);
    // L3. [G6 256 | G11 256 | smST 2048] = 2560 blocks
    gemm2smw<G6, G11><<<2560, 64, 0, stream>>>(256, 256,
        W_madb, vmrT, nullptr, vmm, 1024, 2048, 1024, 16,
        W_gcnT, vmrT, b_gcn, xT, 1024, 2048, 1024, 16,
        ST);
    // L4. G7: vmaT = ST_sm*vmm + b_mad (2048x1024 K2048), 512 64x64 blocks
    gemm1w<G7><<<512, 64, 0, stream>>>(ST, vmm, b_mad, vmaT, (__bf16*)nullptr,
                                       2048, 1024, 2048, 16);
    // L5. G9: P = vmaT*vmaT^T symmetric (2048x2048 K1024), 528 tri blocks
    gemm1wsym<G9><<<528, 64, 0, stream>>>(vmaT, P, 2048, 1024, 32);
    // L6. softmax rows of P
    row_softmax_w<<<2048, 64, 0, stream>>>(P);
    // L7. G12: out = (P_sm*xT)^T direct fp32 (2048x1024 K2048), 512 blocks
    gemm1w<G12><<<512, 64, 0, stream>>>(P, xT, nullptr, (float*)nullptr, out,
                                        2048, 1024, 2048, 16);
}